// Round 8
// baseline (184.209 us; speedup 1.0000x reference)
//
#include <hip/hip_runtime.h>
#include <hip/hip_bf16.h>

#define NB 4       // batch
#define SEQ 1024
#define EMB 1024
#define NH 16
#define HD 64

typedef unsigned short u16;
typedef __attribute__((ext_vector_type(8))) __bf16 bf16x8;
typedef __attribute__((ext_vector_type(8))) short short8;
typedef __attribute__((ext_vector_type(4))) float floatx4;

// fp32 -> bf16 round-to-nearest-even
__device__ inline u16 f2b_rn(float f) {
    union { float f; unsigned int i; } x; x.f = f;
    unsigned int r = (x.i + 0x7FFFu + ((x.i >> 16) & 1u)) >> 16;
    return (u16)r;
}
__device__ inline bf16x8 s2b(short8 v) {
    union { short8 s; bf16x8 b; } x; x.s = v; return x.b;
}

// async global->LDS, 16 B per lane.  LDS dest = wave-uniform base + lane*16.
__device__ inline void gload_lds16(const void* g, void* l) {
    __builtin_amdgcn_global_load_lds(
        (const __attribute__((address_space(1))) void*)g,
        (__attribute__((address_space(3))) void*)l, 16, 0, 0);
}

// XOR-swizzled fragment read from an unpadded [rows][64] u16 LDS buffer.
// One row = 128 B = all 32 banks; (r&7) XOR spreads 16-lane b128 reads.
__device__ inline bf16x8 ldsfrag(const u16* base, int r, int c) {
    return s2b(*(const short8*)&base[r * 64 + (c ^ ((r & 7) * 8))]);
}

__device__ inline void cvt8(const float* __restrict__ s, u16* __restrict__ d) {
    float4 a = *(const float4*)(s);
    float4 b = *(const float4*)(s + 4);
    union { u16 u[8]; int4 v; } o;
    o.u[0] = f2b_rn(a.x); o.u[1] = f2b_rn(a.y); o.u[2] = f2b_rn(a.z); o.u[3] = f2b_rn(a.w);
    o.u[4] = f2b_rn(b.x); o.u[5] = f2b_rn(b.y); o.u[6] = f2b_rn(b.z); o.u[7] = f2b_rn(b.w);
    *(int4*)(d) = o.v;
}

// sync/wait macros (all defined BEFORE first use)
#define BARX do { __builtin_amdgcn_sched_barrier(0); __builtin_amdgcn_s_barrier(); __builtin_amdgcn_sched_barrier(0); } while(0)
#define VMCNT6 asm volatile("s_waitcnt vmcnt(6)" ::: "memory")
#define VMCNT5 asm volatile("s_waitcnt vmcnt(5)" ::: "memory")
#define VMCNT2 asm volatile("s_waitcnt vmcnt(2)" ::: "memory")
#define VMCNT0 asm volatile("s_waitcnt vmcnt(0)" ::: "memory")

// ---------------------------------------------------------------------------
// Kernel P: prep.  blockIdx.x ranges (Wo convert lives here — r8: the safe
// half of r7; r7's attn bits-reorder raced and is reverted):
//   [0,512)      x fp32->bf16   (4 x 2048 elems per block)
//   [512,1280)   W transpose+convert -> Wt[3072][1024]
//   [1280,1792)  Wo fp32->bf16 (512 blocks x 2048 elems)
//   [1792,5888)  mask -> bitmask (4096 blocks x 16 rows; 4 rows/wave)
// ---------------------------------------------------------------------------
__global__ __launch_bounds__(256) void prep(
    const float* __restrict__ x, const float* __restrict__ Wq,
    const float* __restrict__ Wk, const float* __restrict__ Wv,
    const float* __restrict__ Wo, const int* __restrict__ mask,
    u16* __restrict__ xb, u16* __restrict__ Wt, u16* __restrict__ Wob,
    unsigned long long* __restrict__ bits)
{
    __shared__ u16 T[64 * 80];
    int bx = blockIdx.x;
    int tid = threadIdx.x;

    if (bx < 512) {
        #pragma unroll
        for (int c = 0; c < 4; ++c) {
            int i = (bx * 4 + c) * 2048 + tid * 8;
            cvt8(x + i, xb + i);
        }
    } else if (bx < 1280) {
        int bx2 = bx - 512;
        int e0 = (bx2 & 15) * 64;
        int ph = bx2 >> 4;              // 0..47
        int p = ph >> 4, h = ph & 15;
        const float* W = (p == 0 ? Wq : (p == 1 ? Wk : Wv)) + h * (EMB * HD);
        #pragma unroll
        for (int c = 0; c < 2; ++c) {
            int flat = c * 2048 + tid * 8;
            int r = flat >> 6;
            int d = flat & 63;
            cvt8(W + (size_t)(e0 + r) * HD + d, &T[r * 80 + d]);
        }
        __syncthreads();
        int d = tid >> 2;
        int ec = tid & 3;
        union { u16 u[16]; int4 v[2]; } tmp;
        #pragma unroll
        for (int i = 0; i < 16; ++i) tmp.u[i] = T[(ec * 16 + i) * 80 + d];
        u16* dst = Wt + ((size_t)(p * NH + h) * HD + d) * EMB + e0 + ec * 16;
        *(int4*)(dst) = tmp.v[0];
        *(int4*)(dst + 8) = tmp.v[1];
    } else if (bx < 1792) {
        int i = (bx - 1280) * 2048 + tid * 8;
        cvt8(Wo + i, Wob + i);
    } else {
        int base = (bx - 1792) * 16 + (tid >> 6) * 4;    // 4 waves x 4 rows
        int lane = tid & 63;
        #pragma unroll
        for (int i = 0; i < 4; ++i) {
            int gw = base + i;                            // 0..65535
            int m = mask[(size_t)gw * 64 + lane];
            unsigned long long bl = __ballot(m != 0);
            if (lane == 0) bits[gw] = bl;
        }
    }
}

// ---------------------------------------------------------------------------
// Kernel 1: fused QKV GEMM v3 — 256x192 tile, 16x16 = 256 blocks (full CU
// coverage), 8 waves, 8-phase counted-vmcnt schedule (verified round 6,
// 183.9 -> 177.8).  Unchanged.
// ---------------------------------------------------------------------------
__device__ __forceinline__ void rd_b3(const u16* B, int wn, int ln, int quad, bf16x8 (&bfr)[3][2]) {
    #pragma unroll
    for (int nc = 0; nc < 3; ++nc) {
        bfr[nc][0] = ldsfrag(B, wn * 48 + nc * 16 + ln, quad * 8);
        bfr[nc][1] = ldsfrag(B, wn * 48 + nc * 16 + ln, 32 + quad * 8);
    }
}
__device__ __forceinline__ void rd_a(const u16* A, int wm, int mf0, int ln, int quad, bf16x8 (&a)[2][2]) {
    #pragma unroll
    for (int jj = 0; jj < 2; ++jj) {
        a[jj][0] = ldsfrag(A, wm * 128 + (mf0 + jj) * 16 + ln, quad * 8);
        a[jj][1] = ldsfrag(A, wm * 128 + (mf0 + jj) * 16 + ln, 32 + quad * 8);
    }
}
__device__ __forceinline__ void mm12(floatx4 (&acc)[8][3], const bf16x8 (&a)[2][2],
                                     const bf16x8 (&bfr)[3][2], int mf0) {
    #pragma unroll
    for (int jj = 0; jj < 2; ++jj)
        #pragma unroll
        for (int nc = 0; nc < 3; ++nc) {
            acc[mf0 + jj][nc] = __builtin_amdgcn_mfma_f32_16x16x32_bf16(a[jj][0], bfr[nc][0], acc[mf0 + jj][nc], 0, 0, 0);
            acc[mf0 + jj][nc] = __builtin_amdgcn_mfma_f32_16x16x32_bf16(a[jj][1], bfr[nc][1], acc[mf0 + jj][nc], 0, 0, 0);
        }
}

// stage one 64-row chunk: src rows pre-swizzled so linear LDS dest + XOR read
// are conflict-free (rule 21: inverse-swz SOURCE + swz READ, involution).
#define STG(srcb, buf, c, kt) gload_lds16((srcb) + (size_t)(c) * 65536 + (kt) * 64 + soff, (buf) + (c) * 4096 + ldst)

__global__ __launch_bounds__(512, 2) void qkv_gemm(
    const u16* __restrict__ x,    // bf16 [4096][1024]
    const u16* __restrict__ Wt2,  // bf16 [3072][1024]
    const float* __restrict__ bq, const float* __restrict__ bk, const float* __restrict__ bv,
    u16* __restrict__ Q, u16* __restrict__ K, u16* __restrict__ Vt)
{
    __shared__ u16 L[57344];                  // 112 KiB
    u16* A0s = L;                             // 256x64
    u16* A1s = L + 16384;
    u16* B0s = L + 32768;                     // 192x64
    u16* B1s = L + 45056;

    int gid = blockIdx.x;
    int xcd = gid & 7;                        // 0..7
    int j   = gid >> 3;                       // 0..31
    int mt_ = (xcd >> 1) * 4 + (j & 3);       // 0..15
    int nt_ = (xcd & 1) * 8 + (j >> 2);       // 0..15
    int m0 = mt_ * 256;
    int n0 = nt_ * 192;

    int tid = threadIdx.x;
    int w = tid >> 6, lane = tid & 63, quad = lane >> 4, ln = lane & 15;
    int wm = w >> 2, wn = w & 3;              // 2 x 4 wave grid

    const u16* Asrc = x   + (size_t)m0 * EMB;
    const u16* Bsrc = Wt2 + (size_t)n0 * EMB;

    // per-lane stage addressing: flat = tid; r = flat>>3 in [0,64); pre-swz col
    int sr = tid >> 3;
    int sc = ((tid & 7) ^ (sr & 7)) * 8;
    size_t soff = (size_t)sr * EMB + sc;
    int ldst = w * 512;                       // u16 elems: wave-uniform LDS base

    // ---- prologue: tile0 all 7, tile1 first 5 (steady-state order)
    STG(Asrc, A0s, 0, 0); STG(Asrc, A0s, 1, 0); STG(Asrc, A0s, 2, 0); STG(Asrc, A0s, 3, 0);
    STG(Bsrc, B0s, 0, 0); STG(Bsrc, B0s, 1, 0); STG(Bsrc, B0s, 2, 0);
    STG(Bsrc, B1s, 0, 1); STG(Bsrc, B1s, 1, 1); STG(Bsrc, B1s, 2, 1);
    STG(Asrc, A1s, 0, 1); STG(Asrc, A1s, 2, 1);
    VMCNT5;                                   // tile0's 7 stages landed
    BARX;

    floatx4 acc[8][3] = {};
    bf16x8 bfr[3][2];
    bf16x8 a[2][2];

    for (int i = 0; i < 8; ++i) {
        const int T = 2 * i;
        const bool st = (i < 7);
        // ---- P1
        rd_b3(B0s, wn, ln, quad, bfr);
        rd_a(A0s, wm, 0, ln, quad, a);
        STG(Asrc, A1s, 1, T + 1); STG(Asrc, A1s, 3, T + 1);   // T+1 finals
        BARX;
        __builtin_amdgcn_s_setprio(1); mm12(acc, a, bfr, 0); __builtin_amdgcn_s_setprio(0);
        BARX;
        // ---- P2
        rd_a(A0s, wm, 2, ln, quad, a);
        if (st) { STG(Bsrc, B0s, 0, T + 2); STG(Bsrc, B0s, 1, T + 2); }
        BARX;
        __builtin_amdgcn_s_setprio(1); mm12(acc, a, bfr, 2); __builtin_amdgcn_s_setprio(0);
        BARX;
        // ---- P3
        rd_a(A0s, wm, 4, ln, quad, a);
        if (st) { STG(Bsrc, B0s, 2, T + 2); STG(Asrc, A0s, 0, T + 2); }
        BARX;
        __builtin_amdgcn_s_setprio(1); mm12(acc, a, bfr, 4); __builtin_amdgcn_s_setprio(0);
        BARX;
        // ---- P4
        rd_a(A0s, wm, 6, ln, quad, a);
        if (st) { STG(Asrc, A0s, 2, T + 2); }
        BARX;
        __builtin_amdgcn_s_setprio(1); mm12(acc, a, bfr, 6); __builtin_amdgcn_s_setprio(0);
        if (st) { VMCNT5; } else { VMCNT0; }  // tile T+1 fully landed
        BARX;
        // ---- P5
        rd_b3(B1s, wn, ln, quad, bfr);
        rd_a(A1s, wm, 0, ln, quad, a);
        if (st) { STG(Asrc, A0s, 1, T + 2); STG(Asrc, A0s, 3, T + 2); }  // T+2 finals
        BARX;
        __builtin_amdgcn_s_setprio(1); mm12(acc, a, bfr, 0); __builtin_amdgcn_s_setprio(0);
        BARX;
        // ---- P6
        rd_a(A1s, wm, 2, ln, quad, a);
        if (st) { STG(Bsrc, B1s, 0, T + 3); STG(Bsrc, B1s, 1, T + 3); }
        BARX;
        __builtin_amdgcn_s_setprio(1); mm12(acc, a, bfr, 2); __builtin_amdgcn_s_setprio(0);
        BARX;
        // ---- P7
        rd_a(A1s, wm, 4, ln, quad, a);
        if (st) { STG(Bsrc, B1s, 2, T + 3); STG(Asrc, A1s, 0, T + 3); }
        BARX;
        __builtin_amdgcn_s_setprio(1); mm12(acc, a, bfr, 4); __builtin_amdgcn_s_setprio(0);
        BARX;
        // ---- P8
        rd_a(A1s, wm, 6, ln, quad, a);
        if (st) { STG(Asrc, A1s, 2, T + 3); }
        BARX;
        __builtin_amdgcn_s_setprio(1); mm12(acc, a, bfr, 6); __builtin_amdgcn_s_setprio(0);
        if (st) { VMCNT5; }                   // tile T+2 fully landed
        BARX;
    }

    // ---- epilogue: p,h per 16-col chunk (16-aligned chunk never crosses
    // a head or Q/K/V boundary)
    int nb_w = n0 + wn * 48;
    #pragma unroll
    for (int nc = 0; nc < 3; ++nc) {
        int nbc = nb_w + nc * 16;             // wave-uniform, 16-aligned
        int p = nbc >> 10;
        int h = (nbc >> 6) & 15;
        const float* bias = (p == 0 ? bq : (p == 1 ? bk : bv));
        int d = (nbc & 63) + ln;
        float bv_ = bias[(nbc & 1023) + ln];
        if (p < 2) {
            u16* Out = (p == 0) ? Q : K;
            float qs = (p == 0) ? 0.125f * 1.44269504f : 1.0f;   // fold 1/sqrt(64), log2(e)
            #pragma unroll
            for (int mf = 0; mf < 8; ++mf) {
                #pragma unroll
                for (int reg = 0; reg < 4; ++reg) {
                    int m = m0 + wm * 128 + mf * 16 + quad * 4 + reg;
                    int b_ = m >> 10, s = m & 1023;
                    Out[((size_t)(b_ * NH + h) * SEQ + s) * HD + d] = f2b_rn((acc[mf][nc][reg] + bv_) * qs);
                }
            }
        } else {
            #pragma unroll
            for (int mf = 0; mf < 8; ++mf) {
                int m = m0 + wm * 128 + mf * 16 + quad * 4;
                int b_ = m >> 10, s = m & 1023;
                union { u16 u[4]; uint2 v; } pk;
                #pragma unroll
                for (int reg = 0; reg < 4; ++reg)
                    pk.u[reg] = f2b_rn(acc[mf][nc][reg] + bv_);
                *(uint2*)&Vt[((size_t)(b_ * NH + h) * HD + d) * SEQ + s] = pk.v;
            }
        }
    }
}

// ---------------------------------------------------------------------------
// Kernel 2: flash attention v7 — 128-row q-tiles + 2-phase double-buffered
// K/V pipeline with counted vmcnt.  EXACT round-6-verified logic (r7's bits
// reorder raced; reverted).  Steady-state trace shows the buf1 stage stays
// in flight through buf0 compute (compiler's mask auto-wait = vmcnt(6)),
// so the pipeline overlap is real from iter 1 on.  Wo tail moved to prep ->
// grid 512 pure attention.
// ---------------------------------------------------------------------------
__device__ __forceinline__ void astage(const u16* __restrict__ Kb, const u16* __restrict__ Vb,
                                       u16* Kd, u16* Vd, int t0, int tid) {
    #pragma unroll
    for (int i = 0; i < 2; ++i) {
        int flat0 = i * 256 + (tid & 192);
        int flat = flat0 + (tid & 63);
        int r = flat >> 3;
        int c = ((flat & 7) ^ (r & 7)) * 8;
        gload_lds16(Kb + (size_t)(t0 + r) * HD + c, Kd + flat0 * 8);
        gload_lds16(Vb + (size_t)r * SEQ + t0 + c, Vd + flat0 * 8);
    }
}

__device__ __forceinline__ void attn_tile(
    const u16* Ksc, const u16* Vsc, u16* Ps,
    const bf16x8 (&qf)[2][2], floatx4 (&o)[2][5],
    unsigned long long bm0, unsigned long long bm1,
    int w, int ln, int quad)
{
    const int PP = 72;
    floatx4 sc[2][4] = {};
    #pragma unroll
    for (int kk = 0; kk < 2; ++kk) {
        bf16x8 kf[4];
        #pragma unroll
        for (int tb = 0; tb < 4; ++tb)
            kf[tb] = ldsfrag(Ksc, tb * 16 + ln, kk * 32 + quad * 8);
        __builtin_amdgcn_s_setprio(1);
        #pragma unroll
        for (int s = 0; s < 2; ++s)
            #pragma unroll
            for (int tb = 0; tb < 4; ++tb)
                sc[s][tb] = __builtin_amdgcn_mfma_f32_16x16x32_bf16(kf[tb], qf[s][kk], sc[s][tb], 0, 0, 0);
        __builtin_amdgcn_s_setprio(0);
    }

    #pragma unroll
    for (int s = 0; s < 2; ++s) {
        unsigned long long bm = s ? bm1 : bm0;
        if (__any(bm != ~0ull)) {
            #pragma unroll
            for (int tb = 0; tb < 4; ++tb)
                #pragma unroll
                for (int reg = 0; reg < 4; ++reg)
                    if (!((bm >> (tb * 16 + quad * 4 + reg)) & 1)) sc[s][tb][reg] = -1e30f;
        }
    }

    // P = exp2(S), pack 4 consecutive t -> b64 LDS write (per-wave rows)
    #pragma unroll
    for (int s = 0; s < 2; ++s) {
        int mrow = w * 32 + s * 16 + ln;
        #pragma unroll
        for (int tb = 0; tb < 4; ++tb) {
            union { float f; unsigned int i; } e0_, e1_, e2_, e3_;
            e0_.f = __builtin_amdgcn_exp2f(sc[s][tb][0]);
            e1_.f = __builtin_amdgcn_exp2f(sc[s][tb][1]);
            e2_.f = __builtin_amdgcn_exp2f(sc[s][tb][2]);
            e3_.f = __builtin_amdgcn_exp2f(sc[s][tb][3]);
            uint2 pk;
            pk.x = ((e0_.i + 0x8000u) >> 16) | ((e1_.i + 0x8000u) & 0xFFFF0000u);
            pk.y = ((e2_.i + 0x8000u) >> 16) | ((e3_.i + 0x8000u) & 0xFFFF0000u);
            *(uint2*)&Ps[mrow * PP + tb * 16 + quad * 4] = pk;
        }
    }

    // O += P V  (l accumulates in dt=4 via the ones row)
    #pragma unroll
    for (int kk = 0; kk < 2; ++kk) {
        bf16x8 vf[5];
        #pragma unroll
        for (int dt = 0; dt < 5; ++dt)
            vf[dt] = ldsfrag(Vsc, dt * 16 + ln, kk * 32 + quad * 8);
        #pragma unroll
        for (int s = 0; s < 2; ++s) {
            bf16x8 pf = s2b(*(const short8*)&Ps[(w * 32 + s * 16 + ln) * PP + kk * 32 + quad * 8]);
            __builtin_amdgcn_s_setprio(1);
            #pragma unroll
            for (int dt = 0; dt < 5; ++dt)
                o[s][dt] = __builtin_amdgcn_mfma_f32_16x16x32_bf16(pf, vf[dt], o[s][dt], 0, 0, 0);
            __builtin_amdgcn_s_setprio(0);
        }
    }
}

__global__ __launch_bounds__(256) void attn(
    const u16* __restrict__ Q, const u16* __restrict__ K, const u16* __restrict__ Vt,
    const unsigned long long* __restrict__ bits,
    u16* __restrict__ Aout)         // bf16 [B][S][E]
{
    __shared__ u16 L[16512 + 128 * 72];   // 25728 u16 = 50.25 KB
    u16* Ks0 = L;
    u16* Ks1 = L + 4096;
    u16* Vs0 = L + 8192;     // ones row 64 at abs 12288
    u16* Vs1 = L + 12352;    // ones row 64 at abs 16448
    u16* Ps  = L + 16512;

    int bid = blockIdx.x;
    int tid = threadIdx.x;

    int bh = bid & 63;
    int q0 = (bid >> 6) * 128;
    int b = bh >> 4, h = bh & 15;
    const u16* Qb = Q  + (size_t)bh * SEQ * HD;
    const u16* Kb = K  + (size_t)bh * SEQ * HD;
    const u16* Vb = Vt + (size_t)bh * HD * SEQ;   // [d][s]

    int w = tid >> 6, lane = tid & 63, quad = lane >> 4, ln = lane & 15;

    if (tid < 32) {
        u16* dst = (tid < 16 ? L + 12288 : L + 16448) + (tid & 15) * 4;
        *(uint2*)dst = make_uint2(0x3F803F80u, 0x3F803F80u);
    }

    // Q B-fragments: wave w owns strips (w*32 .. w*32+31), 2 strips of 16
    bf16x8 qf[2][2];
    #pragma unroll
    for (int s = 0; s < 2; ++s) {
        const u16* qp = Qb + (size_t)(q0 + w * 32 + s * 16 + ln) * HD + quad * 8;
        union { int4 i; bf16x8 b; } c0, c1;
        c0.i = *(const int4*)(qp);
        c1.i = *(const int4*)(qp + 32);
        qf[s][0] = c0.b; qf[s][1] = c1.b;
    }

    __syncthreads();   // ones rows visible; nothing critical in flight yet

    // prologue: stage tiles 0,1; bits for tile 0 issued AFTER the stages
    astage(Kb, Vb, Ks0, Vs0, 0,  tid);
    astage(Kb, Vb, Ks1, Vs1, 64, tid);
    size_t bb0 = ((size_t)b * SEQ + q0 + w * 32 + ln) * 16;
    size_t bb1 = bb0 + 256;
    unsigned long long bmn0 = bits[bb0];
    unsigned long long bmn1 = bits[bb1];

    floatx4 o[2][5] = {};   // [strip][dt], dt=4 is the l column

    for (int i = 0; i < 8; ++i) {
        // ---- tile 2i (buf0)
        VMCNT6;                         // stage(2i) landed; (bits, stage(2i+1)) in flight
        BARX;
        {
            unsigned long long bc0 = bmn0, bc1 = bmn1;
            bmn0 = bits[bb0 + (2 * i + 1)];     // issued before stage(2i+2)
            bmn1 = bits[bb1 + (2 * i + 1)];
            attn_tile(Ks0, Vs0, Ps, qf, o, bc0, bc1, w, ln, quad);
        }
        BARX;                           // all waves done reading buf0
        if (i < 7) astage(Kb, Vb, Ks0, Vs0, i * 128 + 128, tid);   // tile 2i+2
        // ---- tile 2i+1 (buf1)
        if (i < 7) { VMCNT6; } else { VMCNT2; }
        BARX;
        {
            unsigned long long bc0 = bmn0, bc1 = bmn1;
            if (i < 7) { bmn0 = bits[bb0 + (2 * i + 2)]; bmn1 = bits[bb1 + (2 * i + 2)]; }
            attn_tile(Ks1, Vs1, Ps, qf, o, bc0, bc1, w, ln, quad);
        }
        BARX;                           // all waves done reading buf1
        if (i < 7) astage(Kb, Vb, Ks1, Vs1, i * 128 + 192, tid);   // tile 2i+3
    }

    #pragma unroll
    for (int s = 0; s < 2; ++s) {
        #pragma unroll
        for (int reg = 0; reg < 4; ++reg) {
            float l = __shfl(o[s][4][reg], lane & 48, 64);
            float inv = 1.0f / l;
            int m = q0 + w * 32 + s * 16 + quad * 4 + reg;
            #pragma unroll
            for (int dt = 0; dt < 4; ++dt)
                Aout[((size_t)b * SEQ + m) * EMB + h * HD + dt * 16 + ln] = f2b_rn(o[s][dt][reg] * inv);
        }
    }
}

// ---------------------------------------------------------------------------
// Kernel 3: output projection v2 — 64x256 tile (MxN), 256 blocks, 8 waves,
// depth-2 counted-vmcnt pipeline (verified round 5).  Unchanged.
// ---------------------------------------------------------------------------
#define OSTG_A(buf, kt) gload_lds16(Asrc + (size_t)(kt) * 64 + soff, (buf) + ldst)
#define OSTG_B(buf, c, kt) gload_lds16(Bsrc + (size_t)(c) * 65536 + (size_t)(kt) * 64 + soff, (buf) + (c) * 4096 + ldst)

__device__ __forceinline__ void op_tile(const u16* As, const u16* Bs,
                                        floatx4 (&acc)[4][2], int w, int ln, int quad)
{
    #pragma unroll
    for (int kk = 0; kk < 2; ++kk) {
        bf16x8 av[4], bv2[2];
        #pragma unroll
        for (int mf = 0; mf < 4; ++mf)
            av[mf] = ldsfrag(As, mf * 16 + ln, kk * 32 + quad * 8);
        #pragma unroll
        for (int nc = 0; nc < 2; ++nc)
            bv2[nc] = ldsfrag(Bs, w * 32 + nc * 16 + ln, kk * 32 + quad * 8);
        __builtin_amdgcn_s_setprio(1);
        #pragma unroll
        for (int mf = 0; mf < 4; ++mf)
            #pragma unroll
            for (int nc = 0; nc < 2; ++nc)
                acc[mf][nc] = __builtin_amdgcn_mfma_f32_16x16x32_bf16(av[mf], bv2[nc], acc[mf][nc], 0, 0, 0);
        __builtin_amdgcn_s_setprio(0);
    }
}

__global__ __launch_bounds__(512, 2) void out_proj(
    const u16* __restrict__ A,    // bf16 [4096][1024]
    const u16* __restrict__ Wo,   // bf16 [1024][1024] (n,k)
    const float* __restrict__ bo,
    float* __restrict__ Out)
{
    __shared__ u16 L[40960];                  // 80 KiB
    u16* A0s = L;
    u16* A1s = L + 4096;
    u16* B0s = L + 8192;
    u16* B1s = L + 24576;

    int gid = blockIdx.x;
    int xcd = gid & 7;                        // 0..7
    int j   = gid >> 3;                       // 0..31
    int m0 = (xcd * 8 + (j & 7)) * 64;        // m-tile 0..63
    int n0 = (j >> 3) * 256;                  // n-tile 0..3

    int tid = threadIdx.x;
    int w = tid >> 6, lane = tid & 63, quad = lane >> 4, ln = lane & 15;

    const u16* Asrc = A  + (size_t)m0 * EMB;
    const u16* Bsrc = Wo + (size_t)n0 * EMB;
    int sr = tid >> 3;
    int sc = ((tid & 7) ^ (sr & 7)) * 8;
    size_t soff = (size_t)sr * EMB + sc;
    int ldst = w * 512;

    // prologue: tiles 0 (buf0) and 1 (buf1), 5 chunks each
    OSTG_A(A0s, 0); OSTG_B(B0s, 0, 0); OSTG_B(B0s, 1, 0); OSTG_B(B0s, 2, 0); OSTG_B(B0s, 3, 0);
    OSTG_A(A1s, 1); OSTG_B(B1s, 0, 1); OSTG_B(B1s, 1, 1); OSTG_B(B1s, 2, 1); OSTG_B(B1s, 3, 1);

    floatx4 acc[4][2] = {};

    for (int i = 0; i < 8; ++i) {
        VMCNT5;                         // tile 2i landed (tile 2i+1's 5 in flight)
        BARX;
        op_tile(A0s, B0s, acc, w, ln, quad);
        BARX;                           // all waves done reading buf0
        if (i < 7) {
            int kt = 2 * i + 2;
            OSTG_A(A0s, kt); OSTG_B(B0s, 0, kt); OSTG_B(B0s, 1, kt); OSTG_B(B0s, 2, kt); OSTG_B(B0s, 3, kt);
        }
        if (i < 7) { VMCNT5; } else { VMCNT0; }
        BARX;
        op_tile(A1s, B1s, acc, w, ln, quad);
        BARX;                           // all waves done reading buf1
        if (i < 7) {
            int kt = 2 * i + 3;
            OSTG_A(A1s, kt); OSTG_B(B1s, 0, kt); OSTG_B(B1s, 1, kt); OSTG_B(B1s, 2, kt); OSTG_B(B1s, 3, kt);
        }
    }

    #pragma unroll
    for (int nc = 0; nc < 2; ++nc) {
        int n = n0 + w * 32 + nc * 16 + ln;
        float bb = bo[n];
        #pragma unroll
        for (int mf = 0; mf < 4; ++mf) {
            #pragma unroll
            for (int reg = 0; reg < 4; ++reg) {
                int m = m0 + mf * 16 + quad * 4 + reg;
                Out[(size_t)m * EMB + n] = acc[mf][nc][reg] + bb;
            }
        }
    }
}

// ---------------------------------------------------------------------------
extern "C" void kernel_launch(void* const* d_in, const int* in_sizes, int n_in,
                              void* d_out, int out_size, void* d_ws, size_t ws_size,
                              hipStream_t stream) {
    const float* x  = (const float*)d_in[0];
    const int*   mk = (const int*)d_in[1];
    const float* Wq = (const float*)d_in[2];
    const float* bq = (const float*)d_in[3];
    const float* Wk = (const float*)d_in[4];
    const float* bk = (const float*)d_in[5];
    const float* Wv = (const float*)d_in[6];
    const float* bv = (const float*)d_in[7];
    const float* Wo = (const float*)d_in[8];
    const float* bo = (const float*)d_in[9];
    float* out = (float*)d_out;

    const size_t MB = 1u << 20;
    char* ws = (char*)d_ws;
    u16* xb  = (u16*)ws;                                   // [ 0, 8M)
    u16* Wt  = (u16*)(ws + 8 * MB);                        // [ 8,14M)
    u16* Wob = (u16*)(ws + 14 * MB);                       // [14,16M)
    unsigned long long* bits = (unsigned long long*)(ws + 16 * MB); // [16,16.5M)
    u16* Qw  = (u16*)(ws + 16 * MB + 512 * 1024);          // [16.5,24.5M)
    u16* Kw  = (u16*)(ws + 24 * MB + 512 * 1024);          // [24.5,32.5M)
    u16* Vtw = (u16*)(ws + 32 * MB + 512 * 1024);          // [32.5,40.5M)
    u16* Ao  = xb;                                         // reuse: xb dead after qkv

    prep<<<5888, 256, 0, stream>>>(x, Wq, Wk, Wv, Wo, mk, xb, Wt, Wob, bits);
    qkv_gemm<<<256, 512, 0, stream>>>(xb, Wt, bq, bk, bv, Qw, Kw, Vtw);
    attn<<<512, 256, 0, stream>>>(Qw, Kw, Vtw, bits, Ao);
    out_proj<<<256, 512, 0, stream>>>(Ao, Wob, bo, out);
}

// Round 9
// 178.193 us; speedup vs baseline: 1.0338x; 1.0338x over previous
//
#include <hip/hip_runtime.h>
#include <hip/hip_bf16.h>

#define NB 4       // batch
#define SEQ 1024
#define EMB 1024
#define NH 16
#define HD 64

typedef unsigned short u16;
typedef __attribute__((ext_vector_type(8))) __bf16 bf16x8;
typedef __attribute__((ext_vector_type(8))) short short8;
typedef __attribute__((ext_vector_type(4))) float floatx4;

// fp32 -> bf16 round-to-nearest-even
__device__ inline u16 f2b_rn(float f) {
    union { float f; unsigned int i; } x; x.f = f;
    unsigned int r = (x.i + 0x7FFFu + ((x.i >> 16) & 1u)) >> 16;
    return (u16)r;
}
__device__ inline bf16x8 s2b(short8 v) {
    union { short8 s; bf16x8 b; } x; x.s = v; return x.b;
}

// async global->LDS, 16 B per lane.  LDS dest = wave-uniform base + lane*16.
__device__ inline void gload_lds16(const void* g, void* l) {
    __builtin_amdgcn_global_load_lds(
        (const __attribute__((address_space(1))) void*)g,
        (__attribute__((address_space(3))) void*)l, 16, 0, 0);
}

// XOR-swizzled fragment read from an unpadded [rows][64] u16 LDS buffer.
// One row = 128 B = all 32 banks; (r&7) XOR spreads 16-lane b128 reads.
__device__ inline bf16x8 ldsfrag(const u16* base, int r, int c) {
    return s2b(*(const short8*)&base[r * 64 + (c ^ ((r & 7) * 8))]);
}

__device__ inline void cvt8(const float* __restrict__ s, u16* __restrict__ d) {
    float4 a = *(const float4*)(s);
    float4 b = *(const float4*)(s + 4);
    union { u16 u[8]; int4 v; } o;
    o.u[0] = f2b_rn(a.x); o.u[1] = f2b_rn(a.y); o.u[2] = f2b_rn(a.z); o.u[3] = f2b_rn(a.w);
    o.u[4] = f2b_rn(b.x); o.u[5] = f2b_rn(b.y); o.u[6] = f2b_rn(b.z); o.u[7] = f2b_rn(b.w);
    *(int4*)(d) = o.v;
}

// sync/wait macros (all defined BEFORE first use)
#define BARX do { __builtin_amdgcn_sched_barrier(0); __builtin_amdgcn_s_barrier(); __builtin_amdgcn_sched_barrier(0); } while(0)
#define VMCNT6 asm volatile("s_waitcnt vmcnt(6)" ::: "memory")
#define VMCNT5 asm volatile("s_waitcnt vmcnt(5)" ::: "memory")
#define VMCNT4 asm volatile("s_waitcnt vmcnt(4)" ::: "memory")
#define VMCNT0 asm volatile("s_waitcnt vmcnt(0)" ::: "memory")

// ---------------------------------------------------------------------------
// Kernel P: prep (r6 arrangement — Wo tail lives in attn; r8's move regressed).
//   [0,512)      x fp32->bf16   (4 x 2048 elems per block)
//   [512,1280)   W transpose+convert -> Wt[3072][1024]
//   [1280,5376)  mask -> bitmask (4096 blocks x 16 rows; 4 rows/wave)
// ---------------------------------------------------------------------------
__global__ __launch_bounds__(256) void prep(
    const float* __restrict__ x, const float* __restrict__ Wq,
    const float* __restrict__ Wk, const float* __restrict__ Wv,
    const int* __restrict__ mask,
    u16* __restrict__ xb, u16* __restrict__ Wt,
    unsigned long long* __restrict__ bits)
{
    __shared__ u16 T[64 * 80];
    int bx = blockIdx.x;
    int tid = threadIdx.x;

    if (bx < 512) {
        #pragma unroll
        for (int c = 0; c < 4; ++c) {
            int i = (bx * 4 + c) * 2048 + tid * 8;
            cvt8(x + i, xb + i);
        }
    } else if (bx < 1280) {
        int bx2 = bx - 512;
        int e0 = (bx2 & 15) * 64;
        int ph = bx2 >> 4;              // 0..47
        int p = ph >> 4, h = ph & 15;
        const float* W = (p == 0 ? Wq : (p == 1 ? Wk : Wv)) + h * (EMB * HD);
        #pragma unroll
        for (int c = 0; c < 2; ++c) {
            int flat = c * 2048 + tid * 8;
            int r = flat >> 6;
            int d = flat & 63;
            cvt8(W + (size_t)(e0 + r) * HD + d, &T[r * 80 + d]);
        }
        __syncthreads();
        int d = tid >> 2;
        int ec = tid & 3;
        union { u16 u[16]; int4 v[2]; } tmp;
        #pragma unroll
        for (int i = 0; i < 16; ++i) tmp.u[i] = T[(ec * 16 + i) * 80 + d];
        u16* dst = Wt + ((size_t)(p * NH + h) * HD + d) * EMB + e0 + ec * 16;
        *(int4*)(dst) = tmp.v[0];
        *(int4*)(dst + 8) = tmp.v[1];
    } else {
        int base = (bx - 1280) * 16 + (tid >> 6) * 4;    // 4 waves x 4 rows
        int lane = tid & 63;
        #pragma unroll
        for (int i = 0; i < 4; ++i) {
            int gw = base + i;                            // 0..65535
            int m = mask[(size_t)gw * 64 + lane];
            unsigned long long bl = __ballot(m != 0);
            if (lane == 0) bits[gw] = bl;
        }
    }
}

// ---------------------------------------------------------------------------
// Kernel 1: fused QKV GEMM v3 — 256x192 tile, 16x16 = 256 blocks (full CU
// coverage), 8 waves, 8-phase counted-vmcnt schedule (verified round 6,
// 183.9 -> 177.8).  Unchanged.
// ---------------------------------------------------------------------------
__device__ __forceinline__ void rd_b3(const u16* B, int wn, int ln, int quad, bf16x8 (&bfr)[3][2]) {
    #pragma unroll
    for (int nc = 0; nc < 3; ++nc) {
        bfr[nc][0] = ldsfrag(B, wn * 48 + nc * 16 + ln, quad * 8);
        bfr[nc][1] = ldsfrag(B, wn * 48 + nc * 16 + ln, 32 + quad * 8);
    }
}
__device__ __forceinline__ void rd_a(const u16* A, int wm, int mf0, int ln, int quad, bf16x8 (&a)[2][2]) {
    #pragma unroll
    for (int jj = 0; jj < 2; ++jj) {
        a[jj][0] = ldsfrag(A, wm * 128 + (mf0 + jj) * 16 + ln, quad * 8);
        a[jj][1] = ldsfrag(A, wm * 128 + (mf0 + jj) * 16 + ln, 32 + quad * 8);
    }
}
__device__ __forceinline__ void mm12(floatx4 (&acc)[8][3], const bf16x8 (&a)[2][2],
                                     const bf16x8 (&bfr)[3][2], int mf0) {
    #pragma unroll
    for (int jj = 0; jj < 2; ++jj)
        #pragma unroll
        for (int nc = 0; nc < 3; ++nc) {
            acc[mf0 + jj][nc] = __builtin_amdgcn_mfma_f32_16x16x32_bf16(a[jj][0], bfr[nc][0], acc[mf0 + jj][nc], 0, 0, 0);
            acc[mf0 + jj][nc] = __builtin_amdgcn_mfma_f32_16x16x32_bf16(a[jj][1], bfr[nc][1], acc[mf0 + jj][nc], 0, 0, 0);
        }
}

// stage one 64-row chunk: src rows pre-swizzled so linear LDS dest + XOR read
// are conflict-free (rule 21: inverse-swz SOURCE + swz READ, involution).
#define STG(srcb, buf, c, kt) gload_lds16((srcb) + (size_t)(c) * 65536 + (kt) * 64 + soff, (buf) + (c) * 4096 + ldst)

__global__ __launch_bounds__(512, 2) void qkv_gemm(
    const u16* __restrict__ x,    // bf16 [4096][1024]
    const u16* __restrict__ Wt2,  // bf16 [3072][1024]
    const float* __restrict__ bq, const float* __restrict__ bk, const float* __restrict__ bv,
    u16* __restrict__ Q, u16* __restrict__ K, u16* __restrict__ Vt)
{
    __shared__ u16 L[57344];                  // 112 KiB
    u16* A0s = L;                             // 256x64
    u16* A1s = L + 16384;
    u16* B0s = L + 32768;                     // 192x64
    u16* B1s = L + 45056;

    int gid = blockIdx.x;
    int xcd = gid & 7;                        // 0..7
    int j   = gid >> 3;                       // 0..31
    int mt_ = (xcd >> 1) * 4 + (j & 3);       // 0..15
    int nt_ = (xcd & 1) * 8 + (j >> 2);       // 0..15
    int m0 = mt_ * 256;
    int n0 = nt_ * 192;

    int tid = threadIdx.x;
    int w = tid >> 6, lane = tid & 63, quad = lane >> 4, ln = lane & 15;
    int wm = w >> 2, wn = w & 3;              // 2 x 4 wave grid

    const u16* Asrc = x   + (size_t)m0 * EMB;
    const u16* Bsrc = Wt2 + (size_t)n0 * EMB;

    // per-lane stage addressing: flat = tid; r = flat>>3 in [0,64); pre-swz col
    int sr = tid >> 3;
    int sc = ((tid & 7) ^ (sr & 7)) * 8;
    size_t soff = (size_t)sr * EMB + sc;
    int ldst = w * 512;                       // u16 elems: wave-uniform LDS base

    // ---- prologue: tile0 all 7, tile1 first 5 (steady-state order)
    STG(Asrc, A0s, 0, 0); STG(Asrc, A0s, 1, 0); STG(Asrc, A0s, 2, 0); STG(Asrc, A0s, 3, 0);
    STG(Bsrc, B0s, 0, 0); STG(Bsrc, B0s, 1, 0); STG(Bsrc, B0s, 2, 0);
    STG(Bsrc, B1s, 0, 1); STG(Bsrc, B1s, 1, 1); STG(Bsrc, B1s, 2, 1);
    STG(Asrc, A1s, 0, 1); STG(Asrc, A1s, 2, 1);
    VMCNT5;                                   // tile0's 7 stages landed
    BARX;

    floatx4 acc[8][3] = {};
    bf16x8 bfr[3][2];
    bf16x8 a[2][2];

    for (int i = 0; i < 8; ++i) {
        const int T = 2 * i;
        const bool st = (i < 7);
        // ---- P1
        rd_b3(B0s, wn, ln, quad, bfr);
        rd_a(A0s, wm, 0, ln, quad, a);
        STG(Asrc, A1s, 1, T + 1); STG(Asrc, A1s, 3, T + 1);   // T+1 finals
        BARX;
        __builtin_amdgcn_s_setprio(1); mm12(acc, a, bfr, 0); __builtin_amdgcn_s_setprio(0);
        BARX;
        // ---- P2
        rd_a(A0s, wm, 2, ln, quad, a);
        if (st) { STG(Bsrc, B0s, 0, T + 2); STG(Bsrc, B0s, 1, T + 2); }
        BARX;
        __builtin_amdgcn_s_setprio(1); mm12(acc, a, bfr, 2); __builtin_amdgcn_s_setprio(0);
        BARX;
        // ---- P3
        rd_a(A0s, wm, 4, ln, quad, a);
        if (st) { STG(Bsrc, B0s, 2, T + 2); STG(Asrc, A0s, 0, T + 2); }
        BARX;
        __builtin_amdgcn_s_setprio(1); mm12(acc, a, bfr, 4); __builtin_amdgcn_s_setprio(0);
        BARX;
        // ---- P4
        rd_a(A0s, wm, 6, ln, quad, a);
        if (st) { STG(Asrc, A0s, 2, T + 2); }
        BARX;
        __builtin_amdgcn_s_setprio(1); mm12(acc, a, bfr, 6); __builtin_amdgcn_s_setprio(0);
        if (st) { VMCNT5; } else { VMCNT0; }  // tile T+1 fully landed
        BARX;
        // ---- P5
        rd_b3(B1s, wn, ln, quad, bfr);
        rd_a(A1s, wm, 0, ln, quad, a);
        if (st) { STG(Asrc, A0s, 1, T + 2); STG(Asrc, A0s, 3, T + 2); }  // T+2 finals
        BARX;
        __builtin_amdgcn_s_setprio(1); mm12(acc, a, bfr, 0); __builtin_amdgcn_s_setprio(0);
        BARX;
        // ---- P6
        rd_a(A1s, wm, 2, ln, quad, a);
        if (st) { STG(Bsrc, B1s, 0, T + 3); STG(Bsrc, B1s, 1, T + 3); }
        BARX;
        __builtin_amdgcn_s_setprio(1); mm12(acc, a, bfr, 2); __builtin_amdgcn_s_setprio(0);
        BARX;
        // ---- P7
        rd_a(A1s, wm, 4, ln, quad, a);
        if (st) { STG(Bsrc, B1s, 2, T + 3); STG(Asrc, A1s, 0, T + 3); }
        BARX;
        __builtin_amdgcn_s_setprio(1); mm12(acc, a, bfr, 4); __builtin_amdgcn_s_setprio(0);
        BARX;
        // ---- P8
        rd_a(A1s, wm, 6, ln, quad, a);
        if (st) { STG(Asrc, A1s, 2, T + 3); }
        BARX;
        __builtin_amdgcn_s_setprio(1); mm12(acc, a, bfr, 6); __builtin_amdgcn_s_setprio(0);
        if (st) { VMCNT5; }                   // tile T+2 fully landed
        BARX;
    }

    // ---- epilogue: p,h per 16-col chunk (16-aligned chunk never crosses
    // a head or Q/K/V boundary)
    int nb_w = n0 + wn * 48;
    #pragma unroll
    for (int nc = 0; nc < 3; ++nc) {
        int nbc = nb_w + nc * 16;             // wave-uniform, 16-aligned
        int p = nbc >> 10;
        int h = (nbc >> 6) & 15;
        const float* bias = (p == 0 ? bq : (p == 1 ? bk : bv));
        int d = (nbc & 63) + ln;
        float bv_ = bias[(nbc & 1023) + ln];
        if (p < 2) {
            u16* Out = (p == 0) ? Q : K;
            float qs = (p == 0) ? 0.125f * 1.44269504f : 1.0f;   // fold 1/sqrt(64), log2(e)
            #pragma unroll
            for (int mf = 0; mf < 8; ++mf) {
                #pragma unroll
                for (int reg = 0; reg < 4; ++reg) {
                    int m = m0 + wm * 128 + mf * 16 + quad * 4 + reg;
                    int b_ = m >> 10, s = m & 1023;
                    Out[((size_t)(b_ * NH + h) * SEQ + s) * HD + d] = f2b_rn((acc[mf][nc][reg] + bv_) * qs);
                }
            }
        } else {
            #pragma unroll
            for (int mf = 0; mf < 8; ++mf) {
                int m = m0 + wm * 128 + mf * 16 + quad * 4;
                int b_ = m >> 10, s = m & 1023;
                union { u16 u[4]; uint2 v; } pk;
                #pragma unroll
                for (int reg = 0; reg < 4; ++reg)
                    pk.u[reg] = f2b_rn(acc[mf][nc][reg] + bv_);
                *(uint2*)&Vt[((size_t)(b_ * NH + h) * HD + d) * SEQ + s] = pk.v;
            }
        }
    }
}

// ---------------------------------------------------------------------------
// Kernel 2: flash attention v9 — 256-row q-tiles, 512 thr = 8 waves.
// r9 merge: one K/V staging per 256 q-rows (was 128) -> staging VMEM ops,
// K/V global traffic, and barriers per q-row all HALVE; per-wave work and
// total wave count unchanged (2048 waves, 2/SIMD).  At 512 threads one
// gload_lds16 covers a whole 64x64 tile (512 lanes x 16 B = 8 KB): astage
// = 2 VMEM ops.  Counted-vmcnt discipline rescaled from the r6-verified
// trace: steady queue [S(2), b(2), S(2)] -> VMCNT4 at each buffer top
// drains exactly that buffer's stage; mask auto-wait retires bits at
// vmcnt(4), keeping the next stage in flight.  LDS 68.25 KB (Ps 256x72).
//   bid <  256: attn unit; bh = bid & 63, q0 = (bid >> 6) * 256
//   bid >= 256: Wo fp32->bf16 tail (256 blocks x 4096 elems, r6-style)
// ---------------------------------------------------------------------------
__device__ __forceinline__ void astage512(const u16* __restrict__ Kb, const u16* __restrict__ Vb,
                                          u16* Kd, u16* Vd, int t0, int tid) {
    int r = tid >> 3;                          // 0..63
    int c = ((tid & 7) ^ (r & 7)) * 8;         // pre-swizzled col
    int base = (tid >> 6) * 512;               // u16, wave-uniform LDS base
    gload_lds16(Kb + (size_t)(t0 + r) * HD + c, Kd + base);
    gload_lds16(Vb + (size_t)r * SEQ + t0 + c, Vd + base);
}

__device__ __forceinline__ void attn_tile(
    const u16* Ksc, const u16* Vsc, u16* Ps,
    const bf16x8 (&qf)[2][2], floatx4 (&o)[2][5],
    unsigned long long bm0, unsigned long long bm1,
    int w, int ln, int quad)
{
    const int PP = 72;
    floatx4 sc[2][4] = {};
    #pragma unroll
    for (int kk = 0; kk < 2; ++kk) {
        bf16x8 kf[4];
        #pragma unroll
        for (int tb = 0; tb < 4; ++tb)
            kf[tb] = ldsfrag(Ksc, tb * 16 + ln, kk * 32 + quad * 8);
        __builtin_amdgcn_s_setprio(1);
        #pragma unroll
        for (int s = 0; s < 2; ++s)
            #pragma unroll
            for (int tb = 0; tb < 4; ++tb)
                sc[s][tb] = __builtin_amdgcn_mfma_f32_16x16x32_bf16(kf[tb], qf[s][kk], sc[s][tb], 0, 0, 0);
        __builtin_amdgcn_s_setprio(0);
    }

    #pragma unroll
    for (int s = 0; s < 2; ++s) {
        unsigned long long bm = s ? bm1 : bm0;
        if (__any(bm != ~0ull)) {
            #pragma unroll
            for (int tb = 0; tb < 4; ++tb)
                #pragma unroll
                for (int reg = 0; reg < 4; ++reg)
                    if (!((bm >> (tb * 16 + quad * 4 + reg)) & 1)) sc[s][tb][reg] = -1e30f;
        }
    }

    // P = exp2(S), pack 4 consecutive t -> b64 LDS write (per-wave rows)
    #pragma unroll
    for (int s = 0; s < 2; ++s) {
        int mrow = w * 32 + s * 16 + ln;
        #pragma unroll
        for (int tb = 0; tb < 4; ++tb) {
            union { float f; unsigned int i; } e0_, e1_, e2_, e3_;
            e0_.f = __builtin_amdgcn_exp2f(sc[s][tb][0]);
            e1_.f = __builtin_amdgcn_exp2f(sc[s][tb][1]);
            e2_.f = __builtin_amdgcn_exp2f(sc[s][tb][2]);
            e3_.f = __builtin_amdgcn_exp2f(sc[s][tb][3]);
            uint2 pk;
            pk.x = ((e0_.i + 0x8000u) >> 16) | ((e1_.i + 0x8000u) & 0xFFFF0000u);
            pk.y = ((e2_.i + 0x8000u) >> 16) | ((e3_.i + 0x8000u) & 0xFFFF0000u);
            *(uint2*)&Ps[mrow * PP + tb * 16 + quad * 4] = pk;
        }
    }

    // O += P V  (l accumulates in dt=4 via the ones row)
    #pragma unroll
    for (int kk = 0; kk < 2; ++kk) {
        bf16x8 vf[5];
        #pragma unroll
        for (int dt = 0; dt < 5; ++dt)
            vf[dt] = ldsfrag(Vsc, dt * 16 + ln, kk * 32 + quad * 8);
        #pragma unroll
        for (int s = 0; s < 2; ++s) {
            bf16x8 pf = s2b(*(const short8*)&Ps[(w * 32 + s * 16 + ln) * PP + kk * 32 + quad * 8]);
            __builtin_amdgcn_s_setprio(1);
            #pragma unroll
            for (int dt = 0; dt < 5; ++dt)
                o[s][dt] = __builtin_amdgcn_mfma_f32_16x16x32_bf16(pf, vf[dt], o[s][dt], 0, 0, 0);
            __builtin_amdgcn_s_setprio(0);
        }
    }
}

__global__ __launch_bounds__(512) void attn(
    const u16* __restrict__ Q, const u16* __restrict__ K, const u16* __restrict__ Vt,
    const unsigned long long* __restrict__ bits,
    const float* __restrict__ Wo, u16* __restrict__ Wob,
    u16* __restrict__ Aout)         // bf16 [B][S][E]
{
    __shared__ u16 L[16512 + 256 * 72];   // 34944 u16 = 68.25 KB
    u16* Ks0 = L;
    u16* Ks1 = L + 4096;
    u16* Vs0 = L + 8192;     // ones row 64 at abs 12288
    u16* Vs1 = L + 12352;    // ones row 64 at abs 16448
    u16* Ps  = L + 16512;    // 256 x 72

    int bid = blockIdx.x;
    int tid = threadIdx.x;

    if (bid >= 256) {                // Wo convert tail (r6-style placement)
        int i = (bid - 256) * 4096 + tid * 8;
        cvt8(Wo + i, Wob + i);
        return;
    }

    int bh = bid & 63;
    int q0 = (bid >> 6) * 256;
    int b = bh >> 4, h = bh & 15;
    const u16* Qb = Q  + (size_t)bh * SEQ * HD;
    const u16* Kb = K  + (size_t)bh * SEQ * HD;
    const u16* Vb = Vt + (size_t)bh * HD * SEQ;   // [d][s]

    int w = tid >> 6, lane = tid & 63, quad = lane >> 4, ln = lane & 15;

    if (tid < 32) {
        u16* dst = (tid < 16 ? L + 12288 : L + 16448) + (tid & 15) * 4;
        *(uint2*)dst = make_uint2(0x3F803F80u, 0x3F803F80u);
    }

    // Q B-fragments: wave w owns strips (w*32 .. w*32+31), 2 strips of 16
    bf16x8 qf[2][2];
    #pragma unroll
    for (int s = 0; s < 2; ++s) {
        const u16* qp = Qb + (size_t)(q0 + w * 32 + s * 16 + ln) * HD + quad * 8;
        union { int4 i; bf16x8 b; } c0, c1;
        c0.i = *(const int4*)(qp);
        c1.i = *(const int4*)(qp + 32);
        qf[s][0] = c0.b; qf[s][1] = c1.b;
    }

    __syncthreads();   // ones rows visible; nothing critical in flight yet

    // prologue: stage tiles 0,1; bits for tile 0 issued AFTER the stages
    astage512(Kb, Vb, Ks0, Vs0, 0,  tid);
    astage512(Kb, Vb, Ks1, Vs1, 64, tid);
    size_t bb0 = ((size_t)b * SEQ + q0 + w * 32 + ln) * 16;
    size_t bb1 = bb0 + 256;
    unsigned long long bmn0 = bits[bb0];
    unsigned long long bmn1 = bits[bb1];

    floatx4 o[2][5] = {};   // [strip][dt], dt=4 is the l column

    for (int i = 0; i < 8; ++i) {
        // ---- tile 2i (buf0): queue [S(2i)2, b(2i)2, S(2i+1)2] -> drain S(2i)
        VMCNT4;
        BARX;
        {
            unsigned long long bc0 = bmn0, bc1 = bmn1;
            bmn0 = bits[bb0 + (2 * i + 1)];     // issued before stage(2i+2)
            bmn1 = bits[bb1 + (2 * i + 1)];
            attn_tile(Ks0, Vs0, Ps, qf, o, bc0, bc1, w, ln, quad);
        }
        BARX;                           // all waves done reading buf0
        if (i < 7) astage512(Kb, Vb, Ks0, Vs0, i * 128 + 128, tid);   // tile 2i+2
        // ---- tile 2i+1 (buf1)
        if (i < 7) { VMCNT4; } else { VMCNT0; }
        BARX;
        {
            unsigned long long bc0 = bmn0, bc1 = bmn1;
            if (i < 7) { bmn0 = bits[bb0 + (2 * i + 2)]; bmn1 = bits[bb1 + (2 * i + 2)]; }
            attn_tile(Ks1, Vs1, Ps, qf, o, bc0, bc1, w, ln, quad);
        }
        BARX;                           // all waves done reading buf1
        if (i < 7) astage512(Kb, Vb, Ks1, Vs1, i * 128 + 192, tid);   // tile 2i+3
    }

    #pragma unroll
    for (int s = 0; s < 2; ++s) {
        #pragma unroll
        for (int reg = 0; reg < 4; ++reg) {
            float l = __shfl(o[s][4][reg], lane & 48, 64);
            float inv = 1.0f / l;
            int m = q0 + w * 32 + s * 16 + quad * 4 + reg;
            #pragma unroll
            for (int dt = 0; dt < 4; ++dt)
                Aout[((size_t)b * SEQ + m) * EMB + h * HD + dt * 16 + ln] = f2b_rn(o[s][dt][reg] * inv);
        }
    }
}

// ---------------------------------------------------------------------------
// Kernel 3: output projection v2 — 64x256 tile (MxN), 256 blocks, 8 waves,
// depth-2 counted-vmcnt pipeline (verified round 5).  Unchanged.
// ---------------------------------------------------------------------------
#define OSTG_A(buf, kt) gload_lds16(Asrc + (size_t)(kt) * 64 + soff, (buf) + ldst)
#define OSTG_B(buf, c, kt) gload_lds16(Bsrc + (size_t)(c) * 65536 + (size_t)(kt) * 64 + soff, (buf) + (c) * 4096 + ldst)

__device__ __forceinline__ void op_tile(const u16* As, const u16* Bs,
                                        floatx4 (&acc)[4][2], int w, int ln, int quad)
{
    #pragma unroll
    for (int kk = 0; kk < 2; ++kk) {
        bf16x8 av[4], bv2[2];
        #pragma unroll
        for (int mf = 0; mf < 4; ++mf)
            av[mf] = ldsfrag(As, mf * 16 + ln, kk * 32 + quad * 8);
        #pragma unroll
        for (int nc = 0; nc < 2; ++nc)
            bv2[nc] = ldsfrag(Bs, w * 32 + nc * 16 + ln, kk * 32 + quad * 8);
        __builtin_amdgcn_s_setprio(1);
        #pragma unroll
        for (int mf = 0; mf < 4; ++mf)
            #pragma unroll
            for (int nc = 0; nc < 2; ++nc)
                acc[mf][nc] = __builtin_amdgcn_mfma_f32_16x16x32_bf16(av[mf], bv2[nc], acc[mf][nc], 0, 0, 0);
        __builtin_amdgcn_s_setprio(0);
    }
}

__global__ __launch_bounds__(512, 2) void out_proj(
    const u16* __restrict__ A,    // bf16 [4096][1024]
    const u16* __restrict__ Wo,   // bf16 [1024][1024] (n,k)
    const float* __restrict__ bo,
    float* __restrict__ Out)
{
    __shared__ u16 L[40960];                  // 80 KiB
    u16* A0s = L;
    u16* A1s = L + 4096;
    u16* B0s = L + 8192;
    u16* B1s = L + 24576;

    int gid = blockIdx.x;
    int xcd = gid & 7;                        // 0..7
    int j   = gid >> 3;                       // 0..31
    int m0 = (xcd * 8 + (j & 7)) * 64;        // m-tile 0..63
    int n0 = (j >> 3) * 256;                  // n-tile 0..3

    int tid = threadIdx.x;
    int w = tid >> 6, lane = tid & 63, quad = lane >> 4, ln = lane & 15;

    const u16* Asrc = A  + (size_t)m0 * EMB;
    const u16* Bsrc = Wo + (size_t)n0 * EMB;
    int sr = tid >> 3;
    int sc = ((tid & 7) ^ (sr & 7)) * 8;
    size_t soff = (size_t)sr * EMB + sc;
    int ldst = w * 512;

    // prologue: tiles 0 (buf0) and 1 (buf1), 5 chunks each
    OSTG_A(A0s, 0); OSTG_B(B0s, 0, 0); OSTG_B(B0s, 1, 0); OSTG_B(B0s, 2, 0); OSTG_B(B0s, 3, 0);
    OSTG_A(A1s, 1); OSTG_B(B1s, 0, 1); OSTG_B(B1s, 1, 1); OSTG_B(B1s, 2, 1); OSTG_B(B1s, 3, 1);

    floatx4 acc[4][2] = {};

    for (int i = 0; i < 8; ++i) {
        VMCNT5;                         // tile 2i landed (tile 2i+1's 5 in flight)
        BARX;
        op_tile(A0s, B0s, acc, w, ln, quad);
        BARX;                           // all waves done reading buf0
        if (i < 7) {
            int kt = 2 * i + 2;
            OSTG_A(A0s, kt); OSTG_B(B0s, 0, kt); OSTG_B(B0s, 1, kt); OSTG_B(B0s, 2, kt); OSTG_B(B0s, 3, kt);
        }
        if (i < 7) { VMCNT5; } else { VMCNT0; }
        BARX;
        op_tile(A1s, B1s, acc, w, ln, quad);
        BARX;                           // all waves done reading buf1
        if (i < 7) {
            int kt = 2 * i + 3;
            OSTG_A(A1s, kt); OSTG_B(B1s, 0, kt); OSTG_B(B1s, 1, kt); OSTG_B(B1s, 2, kt); OSTG_B(B1s, 3, kt);
        }
    }

    #pragma unroll
    for (int nc = 0; nc < 2; ++nc) {
        int n = n0 + w * 32 + nc * 16 + ln;
        float bb = bo[n];
        #pragma unroll
        for (int mf = 0; mf < 4; ++mf) {
            #pragma unroll
            for (int reg = 0; reg < 4; ++reg) {
                int m = m0 + mf * 16 + quad * 4 + reg;
                Out[(size_t)m * EMB + n] = acc[mf][nc][reg] + bb;
            }
        }
    }
}

// ---------------------------------------------------------------------------
extern "C" void kernel_launch(void* const* d_in, const int* in_sizes, int n_in,
                              void* d_out, int out_size, void* d_ws, size_t ws_size,
                              hipStream_t stream) {
    const float* x  = (const float*)d_in[0];
    const int*   mk = (const int*)d_in[1];
    const float* Wq = (const float*)d_in[2];
    const float* bq = (const float*)d_in[3];
    const float* Wk = (const float*)d_in[4];
    const float* bk = (const float*)d_in[5];
    const float* Wv = (const float*)d_in[6];
    const float* bv = (const float*)d_in[7];
    const float* Wo = (const float*)d_in[8];
    const float* bo = (const float*)d_in[9];
    float* out = (float*)d_out;

    const size_t MB = 1u << 20;
    char* ws = (char*)d_ws;
    u16* xb  = (u16*)ws;                                   // [ 0, 8M)
    u16* Wt  = (u16*)(ws + 8 * MB);                        // [ 8,14M)
    u16* Wob = (u16*)(ws + 14 * MB);                       // [14,16M)
    unsigned long long* bits = (unsigned long long*)(ws + 16 * MB); // [16,16.5M)
    u16* Qw  = (u16*)(ws + 16 * MB + 512 * 1024);          // [16.5,24.5M)
    u16* Kw  = (u16*)(ws + 24 * MB + 512 * 1024);          // [24.5,32.5M)
    u16* Vtw = (u16*)(ws + 32 * MB + 512 * 1024);          // [32.5,40.5M)
    u16* Ao  = xb;                                         // reuse: xb dead after qkv

    prep<<<5376, 256, 0, stream>>>(x, Wq, Wk, Wv, mk, xb, Wt, bits);
    qkv_gemm<<<256, 512, 0, stream>>>(xb, Wt, bq, bk, bv, Qw, Kw, Vtw);
    attn<<<512, 512, 0, stream>>>(Qw, Kw, Vtw, bits, Wo, Wob, Ao);
    out_proj<<<256, 512, 0, stream>>>(Ao, Wob, bo, out);
}

// Round 10
// 177.529 us; speedup vs baseline: 1.0376x; 1.0037x over previous
//
#include <hip/hip_runtime.h>
#include <hip/hip_bf16.h>

#define NB 4       // batch
#define SEQ 1024
#define EMB 1024
#define NH 16
#define HD 64

typedef unsigned short u16;
typedef __attribute__((ext_vector_type(8))) __bf16 bf16x8;
typedef __attribute__((ext_vector_type(8))) short short8;
typedef __attribute__((ext_vector_type(4))) float floatx4;

// fp32 -> bf16 round-to-nearest-even
__device__ inline u16 f2b_rn(float f) {
    union { float f; unsigned int i; } x; x.f = f;
    unsigned int r = (x.i + 0x7FFFu + ((x.i >> 16) & 1u)) >> 16;
    return (u16)r;
}
__device__ inline bf16x8 s2b(short8 v) {
    union { short8 s; bf16x8 b; } x; x.s = v; return x.b;
}

// async global->LDS, 16 B per lane.  LDS dest = wave-uniform base + lane*16.
__device__ inline void gload_lds16(const void* g, void* l) {
    __builtin_amdgcn_global_load_lds(
        (const __attribute__((address_space(1))) void*)g,
        (__attribute__((address_space(3))) void*)l, 16, 0, 0);
}

// XOR-swizzled fragment read from an unpadded [rows][64] u16 LDS buffer.
// One row = 128 B = all 32 banks; (r&7) XOR spreads 16-lane b128 reads.
__device__ inline bf16x8 ldsfrag(const u16* base, int r, int c) {
    return s2b(*(const short8*)&base[r * 64 + (c ^ ((r & 7) * 8))]);
}

__device__ inline void cvt8(const float* __restrict__ s, u16* __restrict__ d) {
    float4 a = *(const float4*)(s);
    float4 b = *(const float4*)(s + 4);
    union { u16 u[8]; int4 v; } o;
    o.u[0] = f2b_rn(a.x); o.u[1] = f2b_rn(a.y); o.u[2] = f2b_rn(a.z); o.u[3] = f2b_rn(a.w);
    o.u[4] = f2b_rn(b.x); o.u[5] = f2b_rn(b.y); o.u[6] = f2b_rn(b.z); o.u[7] = f2b_rn(b.w);
    *(int4*)(d) = o.v;
}

// sync/wait macros (all defined BEFORE first use)
#define BARX do { __builtin_amdgcn_sched_barrier(0); __builtin_amdgcn_s_barrier(); __builtin_amdgcn_sched_barrier(0); } while(0)
#define VMCNT6 asm volatile("s_waitcnt vmcnt(6)" ::: "memory")
#define VMCNT5 asm volatile("s_waitcnt vmcnt(5)" ::: "memory")
#define VMCNT4 asm volatile("s_waitcnt vmcnt(4)" ::: "memory")
#define VMCNT0 asm volatile("s_waitcnt vmcnt(0)" ::: "memory")

// ---------------------------------------------------------------------------
// Kernel P: prep.  blockIdx.x ranges:
//   [0,512)      x fp32->bf16   (4 x 2048 elems per block)
//   [512,1280)   W transpose+convert -> Wt[3072][1024]
//   [1280,5376)  mask -> bitmask, int4-vectorized (r10): lane ln covers row
//                base+w*4+(ln>>4), cols (ln&15)*4..+3; nibble -> shifted u64
//                -> 4-step shfl_xor OR-reduce over the 16-lane row group.
//                16 B/lane (was 4) = 1 KB/wave-load on the 67 MB mask stream.
// ---------------------------------------------------------------------------
__global__ __launch_bounds__(256) void prep(
    const float* __restrict__ x, const float* __restrict__ Wq,
    const float* __restrict__ Wk, const float* __restrict__ Wv,
    const int* __restrict__ mask,
    u16* __restrict__ xb, u16* __restrict__ Wt,
    unsigned long long* __restrict__ bits)
{
    __shared__ u16 T[64 * 80];
    int bx = blockIdx.x;
    int tid = threadIdx.x;

    if (bx < 512) {
        #pragma unroll
        for (int c = 0; c < 4; ++c) {
            int i = (bx * 4 + c) * 2048 + tid * 8;
            cvt8(x + i, xb + i);
        }
    } else if (bx < 1280) {
        int bx2 = bx - 512;
        int e0 = (bx2 & 15) * 64;
        int ph = bx2 >> 4;              // 0..47
        int p = ph >> 4, h = ph & 15;
        const float* W = (p == 0 ? Wq : (p == 1 ? Wk : Wv)) + h * (EMB * HD);
        #pragma unroll
        for (int c = 0; c < 2; ++c) {
            int flat = c * 2048 + tid * 8;
            int r = flat >> 6;
            int d = flat & 63;
            cvt8(W + (size_t)(e0 + r) * HD + d, &T[r * 80 + d]);
        }
        __syncthreads();
        int d = tid >> 2;
        int ec = tid & 3;
        union { u16 u[16]; int4 v[2]; } tmp;
        #pragma unroll
        for (int i = 0; i < 16; ++i) tmp.u[i] = T[(ec * 16 + i) * 80 + d];
        u16* dst = Wt + ((size_t)(p * NH + h) * HD + d) * EMB + e0 + ec * 16;
        *(int4*)(dst) = tmp.v[0];
        *(int4*)(dst + 8) = tmp.v[1];
    } else {
        int w = tid >> 6, ln = tid & 63;
        int gw = (bx - 1280) * 16 + w * 4 + (ln >> 4);    // row 0..65535
        int4 v = ((const int4*)mask)[(size_t)gw * 16 + (ln & 15)];
        unsigned nib = (v.x != 0 ? 1u : 0u) | (v.y != 0 ? 2u : 0u)
                     | (v.z != 0 ? 4u : 0u) | (v.w != 0 ? 8u : 0u);
        unsigned long long part = (unsigned long long)nib << ((ln & 15) * 4);
        part |= __shfl_xor(part, 1);
        part |= __shfl_xor(part, 2);
        part |= __shfl_xor(part, 4);
        part |= __shfl_xor(part, 8);
        if ((ln & 15) == 0) bits[gw] = part;
    }
}

// ---------------------------------------------------------------------------
// Kernel 1: fused QKV GEMM v3 — 256x192 tile, 16x16 = 256 blocks (full CU
// coverage), 8 waves, 8-phase counted-vmcnt schedule (verified round 6,
// 183.9 -> 177.8).  Unchanged.
// ---------------------------------------------------------------------------
__device__ __forceinline__ void rd_b3(const u16* B, int wn, int ln, int quad, bf16x8 (&bfr)[3][2]) {
    #pragma unroll
    for (int nc = 0; nc < 3; ++nc) {
        bfr[nc][0] = ldsfrag(B, wn * 48 + nc * 16 + ln, quad * 8);
        bfr[nc][1] = ldsfrag(B, wn * 48 + nc * 16 + ln, 32 + quad * 8);
    }
}
__device__ __forceinline__ void rd_a(const u16* A, int wm, int mf0, int ln, int quad, bf16x8 (&a)[2][2]) {
    #pragma unroll
    for (int jj = 0; jj < 2; ++jj) {
        a[jj][0] = ldsfrag(A, wm * 128 + (mf0 + jj) * 16 + ln, quad * 8);
        a[jj][1] = ldsfrag(A, wm * 128 + (mf0 + jj) * 16 + ln, 32 + quad * 8);
    }
}
__device__ __forceinline__ void mm12(floatx4 (&acc)[8][3], const bf16x8 (&a)[2][2],
                                     const bf16x8 (&bfr)[3][2], int mf0) {
    #pragma unroll
    for (int jj = 0; jj < 2; ++jj)
        #pragma unroll
        for (int nc = 0; nc < 3; ++nc) {
            acc[mf0 + jj][nc] = __builtin_amdgcn_mfma_f32_16x16x32_bf16(a[jj][0], bfr[nc][0], acc[mf0 + jj][nc], 0, 0, 0);
            acc[mf0 + jj][nc] = __builtin_amdgcn_mfma_f32_16x16x32_bf16(a[jj][1], bfr[nc][1], acc[mf0 + jj][nc], 0, 0, 0);
        }
}

// stage one 64-row chunk: src rows pre-swizzled so linear LDS dest + XOR read
// are conflict-free (rule 21: inverse-swz SOURCE + swz READ, involution).
#define STG(srcb, buf, c, kt) gload_lds16((srcb) + (size_t)(c) * 65536 + (kt) * 64 + soff, (buf) + (c) * 4096 + ldst)

__global__ __launch_bounds__(512, 2) void qkv_gemm(
    const u16* __restrict__ x,    // bf16 [4096][1024]
    const u16* __restrict__ Wt2,  // bf16 [3072][1024]
    const float* __restrict__ bq, const float* __restrict__ bk, const float* __restrict__ bv,
    u16* __restrict__ Q, u16* __restrict__ K, u16* __restrict__ Vt)
{
    __shared__ u16 L[57344];                  // 112 KiB
    u16* A0s = L;                             // 256x64
    u16* A1s = L + 16384;
    u16* B0s = L + 32768;                     // 192x64
    u16* B1s = L + 45056;

    int gid = blockIdx.x;
    int xcd = gid & 7;                        // 0..7
    int j   = gid >> 3;                       // 0..31
    int mt_ = (xcd >> 1) * 4 + (j & 3);       // 0..15
    int nt_ = (xcd & 1) * 8 + (j >> 2);       // 0..15
    int m0 = mt_ * 256;
    int n0 = nt_ * 192;

    int tid = threadIdx.x;
    int w = tid >> 6, lane = tid & 63, quad = lane >> 4, ln = lane & 15;
    int wm = w >> 2, wn = w & 3;              // 2 x 4 wave grid

    const u16* Asrc = x   + (size_t)m0 * EMB;
    const u16* Bsrc = Wt2 + (size_t)n0 * EMB;

    // per-lane stage addressing: flat = tid; r = flat>>3 in [0,64); pre-swz col
    int sr = tid >> 3;
    int sc = ((tid & 7) ^ (sr & 7)) * 8;
    size_t soff = (size_t)sr * EMB + sc;
    int ldst = w * 512;                       // u16 elems: wave-uniform LDS base

    // ---- prologue: tile0 all 7, tile1 first 5 (steady-state order)
    STG(Asrc, A0s, 0, 0); STG(Asrc, A0s, 1, 0); STG(Asrc, A0s, 2, 0); STG(Asrc, A0s, 3, 0);
    STG(Bsrc, B0s, 0, 0); STG(Bsrc, B0s, 1, 0); STG(Bsrc, B0s, 2, 0);
    STG(Bsrc, B1s, 0, 1); STG(Bsrc, B1s, 1, 1); STG(Bsrc, B1s, 2, 1);
    STG(Asrc, A1s, 0, 1); STG(Asrc, A1s, 2, 1);
    VMCNT5;                                   // tile0's 7 stages landed
    BARX;

    floatx4 acc[8][3] = {};
    bf16x8 bfr[3][2];
    bf16x8 a[2][2];

    for (int i = 0; i < 8; ++i) {
        const int T = 2 * i;
        const bool st = (i < 7);
        // ---- P1
        rd_b3(B0s, wn, ln, quad, bfr);
        rd_a(A0s, wm, 0, ln, quad, a);
        STG(Asrc, A1s, 1, T + 1); STG(Asrc, A1s, 3, T + 1);   // T+1 finals
        BARX;
        __builtin_amdgcn_s_setprio(1); mm12(acc, a, bfr, 0); __builtin_amdgcn_s_setprio(0);
        BARX;
        // ---- P2
        rd_a(A0s, wm, 2, ln, quad, a);
        if (st) { STG(Bsrc, B0s, 0, T + 2); STG(Bsrc, B0s, 1, T + 2); }
        BARX;
        __builtin_amdgcn_s_setprio(1); mm12(acc, a, bfr, 2); __builtin_amdgcn_s_setprio(0);
        BARX;
        // ---- P3
        rd_a(A0s, wm, 4, ln, quad, a);
        if (st) { STG(Bsrc, B0s, 2, T + 2); STG(Asrc, A0s, 0, T + 2); }
        BARX;
        __builtin_amdgcn_s_setprio(1); mm12(acc, a, bfr, 4); __builtin_amdgcn_s_setprio(0);
        BARX;
        // ---- P4
        rd_a(A0s, wm, 6, ln, quad, a);
        if (st) { STG(Asrc, A0s, 2, T + 2); }
        BARX;
        __builtin_amdgcn_s_setprio(1); mm12(acc, a, bfr, 6); __builtin_amdgcn_s_setprio(0);
        if (st) { VMCNT5; } else { VMCNT0; }  // tile T+1 fully landed
        BARX;
        // ---- P5
        rd_b3(B1s, wn, ln, quad, bfr);
        rd_a(A1s, wm, 0, ln, quad, a);
        if (st) { STG(Asrc, A0s, 1, T + 2); STG(Asrc, A0s, 3, T + 2); }  // T+2 finals
        BARX;
        __builtin_amdgcn_s_setprio(1); mm12(acc, a, bfr, 0); __builtin_amdgcn_s_setprio(0);
        BARX;
        // ---- P6
        rd_a(A1s, wm, 2, ln, quad, a);
        if (st) { STG(Bsrc, B1s, 0, T + 3); STG(Bsrc, B1s, 1, T + 3); }
        BARX;
        __builtin_amdgcn_s_setprio(1); mm12(acc, a, bfr, 2); __builtin_amdgcn_s_setprio(0);
        BARX;
        // ---- P7
        rd_a(A1s, wm, 4, ln, quad, a);
        if (st) { STG(Bsrc, B1s, 2, T + 3); STG(Asrc, A1s, 0, T + 3); }
        BARX;
        __builtin_amdgcn_s_setprio(1); mm12(acc, a, bfr, 4); __builtin_amdgcn_s_setprio(0);
        BARX;
        // ---- P8
        rd_a(A1s, wm, 6, ln, quad, a);
        if (st) { STG(Asrc, A1s, 2, T + 3); }
        BARX;
        __builtin_amdgcn_s_setprio(1); mm12(acc, a, bfr, 6); __builtin_amdgcn_s_setprio(0);
        if (st) { VMCNT5; }                   // tile T+2 fully landed
        BARX;
    }

    // ---- epilogue: p,h per 16-col chunk (16-aligned chunk never crosses
    // a head or Q/K/V boundary)
    int nb_w = n0 + wn * 48;
    #pragma unroll
    for (int nc = 0; nc < 3; ++nc) {
        int nbc = nb_w + nc * 16;             // wave-uniform, 16-aligned
        int p = nbc >> 10;
        int h = (nbc >> 6) & 15;
        const float* bias = (p == 0 ? bq : (p == 1 ? bk : bv));
        int d = (nbc & 63) + ln;
        float bv_ = bias[(nbc & 1023) + ln];
        if (p < 2) {
            u16* Out = (p == 0) ? Q : K;
            float qs = (p == 0) ? 0.125f * 1.44269504f : 1.0f;   // fold 1/sqrt(64), log2(e)
            #pragma unroll
            for (int mf = 0; mf < 8; ++mf) {
                #pragma unroll
                for (int reg = 0; reg < 4; ++reg) {
                    int m = m0 + wm * 128 + mf * 16 + quad * 4 + reg;
                    int b_ = m >> 10, s = m & 1023;
                    Out[((size_t)(b_ * NH + h) * SEQ + s) * HD + d] = f2b_rn((acc[mf][nc][reg] + bv_) * qs);
                }
            }
        } else {
            #pragma unroll
            for (int mf = 0; mf < 8; ++mf) {
                int m = m0 + wm * 128 + mf * 16 + quad * 4;
                int b_ = m >> 10, s = m & 1023;
                union { u16 u[4]; uint2 v; } pk;
                #pragma unroll
                for (int reg = 0; reg < 4; ++reg)
                    pk.u[reg] = f2b_rn(acc[mf][nc][reg] + bv_);
                *(uint2*)&Vt[((size_t)(b_ * NH + h) * HD + d) * SEQ + s] = pk.v;
            }
        }
    }
}

// ---------------------------------------------------------------------------
// Kernel 2: flash attention v9 — 256-row q-tiles, 512 thr = 8 waves
// (verified round 9; merge was perf-neutral but keeps less traffic).
//   bid <  256: attn unit; bh = bid & 63, q0 = (bid >> 6) * 256
//   bid >= 256: Wo fp32->bf16 tail (256 blocks x 4096 elems)
// ---------------------------------------------------------------------------
__device__ __forceinline__ void astage512(const u16* __restrict__ Kb, const u16* __restrict__ Vb,
                                          u16* Kd, u16* Vd, int t0, int tid) {
    int r = tid >> 3;                          // 0..63
    int c = ((tid & 7) ^ (r & 7)) * 8;         // pre-swizzled col
    int base = (tid >> 6) * 512;               // u16, wave-uniform LDS base
    gload_lds16(Kb + (size_t)(t0 + r) * HD + c, Kd + base);
    gload_lds16(Vb + (size_t)r * SEQ + t0 + c, Vd + base);
}

__device__ __forceinline__ void attn_tile(
    const u16* Ksc, const u16* Vsc, u16* Ps,
    const bf16x8 (&qf)[2][2], floatx4 (&o)[2][5],
    unsigned long long bm0, unsigned long long bm1,
    int w, int ln, int quad)
{
    const int PP = 72;
    floatx4 sc[2][4] = {};
    #pragma unroll
    for (int kk = 0; kk < 2; ++kk) {
        bf16x8 kf[4];
        #pragma unroll
        for (int tb = 0; tb < 4; ++tb)
            kf[tb] = ldsfrag(Ksc, tb * 16 + ln, kk * 32 + quad * 8);
        __builtin_amdgcn_s_setprio(1);
        #pragma unroll
        for (int s = 0; s < 2; ++s)
            #pragma unroll
            for (int tb = 0; tb < 4; ++tb)
                sc[s][tb] = __builtin_amdgcn_mfma_f32_16x16x32_bf16(kf[tb], qf[s][kk], sc[s][tb], 0, 0, 0);
        __builtin_amdgcn_s_setprio(0);
    }

    #pragma unroll
    for (int s = 0; s < 2; ++s) {
        unsigned long long bm = s ? bm1 : bm0;
        if (__any(bm != ~0ull)) {
            #pragma unroll
            for (int tb = 0; tb < 4; ++tb)
                #pragma unroll
                for (int reg = 0; reg < 4; ++reg)
                    if (!((bm >> (tb * 16 + quad * 4 + reg)) & 1)) sc[s][tb][reg] = -1e30f;
        }
    }

    // P = exp2(S), pack 4 consecutive t -> b64 LDS write (per-wave rows)
    #pragma unroll
    for (int s = 0; s < 2; ++s) {
        int mrow = w * 32 + s * 16 + ln;
        #pragma unroll
        for (int tb = 0; tb < 4; ++tb) {
            union { float f; unsigned int i; } e0_, e1_, e2_, e3_;
            e0_.f = __builtin_amdgcn_exp2f(sc[s][tb][0]);
            e1_.f = __builtin_amdgcn_exp2f(sc[s][tb][1]);
            e2_.f = __builtin_amdgcn_exp2f(sc[s][tb][2]);
            e3_.f = __builtin_amdgcn_exp2f(sc[s][tb][3]);
            uint2 pk;
            pk.x = ((e0_.i + 0x8000u) >> 16) | ((e1_.i + 0x8000u) & 0xFFFF0000u);
            pk.y = ((e2_.i + 0x8000u) >> 16) | ((e3_.i + 0x8000u) & 0xFFFF0000u);
            *(uint2*)&Ps[mrow * PP + tb * 16 + quad * 4] = pk;
        }
    }

    // O += P V  (l accumulates in dt=4 via the ones row)
    #pragma unroll
    for (int kk = 0; kk < 2; ++kk) {
        bf16x8 vf[5];
        #pragma unroll
        for (int dt = 0; dt < 5; ++dt)
            vf[dt] = ldsfrag(Vsc, dt * 16 + ln, kk * 32 + quad * 8);
        #pragma unroll
        for (int s = 0; s < 2; ++s) {
            bf16x8 pf = s2b(*(const short8*)&Ps[(w * 32 + s * 16 + ln) * PP + kk * 32 + quad * 8]);
            __builtin_amdgcn_s_setprio(1);
            #pragma unroll
            for (int dt = 0; dt < 5; ++dt)
                o[s][dt] = __builtin_amdgcn_mfma_f32_16x16x32_bf16(pf, vf[dt], o[s][dt], 0, 0, 0);
            __builtin_amdgcn_s_setprio(0);
        }
    }
}

__global__ __launch_bounds__(512) void attn(
    const u16* __restrict__ Q, const u16* __restrict__ K, const u16* __restrict__ Vt,
    const unsigned long long* __restrict__ bits,
    const float* __restrict__ Wo, u16* __restrict__ Wob,
    u16* __restrict__ Aout)         // bf16 [B][S][E]
{
    __shared__ u16 L[16512 + 256 * 72];   // 34944 u16 = 68.25 KB
    u16* Ks0 = L;
    u16* Ks1 = L + 4096;
    u16* Vs0 = L + 8192;     // ones row 64 at abs 12288
    u16* Vs1 = L + 12352;    // ones row 64 at abs 16448
    u16* Ps  = L + 16512;    // 256 x 72

    int bid = blockIdx.x;
    int tid = threadIdx.x;

    if (bid >= 256) {                // Wo convert tail
        int i = (bid - 256) * 4096 + tid * 8;
        cvt8(Wo + i, Wob + i);
        return;
    }

    int bh = bid & 63;
    int q0 = (bid >> 6) * 256;
    int b = bh >> 4, h = bh & 15;
    const u16* Qb = Q  + (size_t)bh * SEQ * HD;
    const u16* Kb = K  + (size_t)bh * SEQ * HD;
    const u16* Vb = Vt + (size_t)bh * HD * SEQ;   // [d][s]

    int w = tid >> 6, lane = tid & 63, quad = lane >> 4, ln = lane & 15;

    if (tid < 32) {
        u16* dst = (tid < 16 ? L + 12288 : L + 16448) + (tid & 15) * 4;
        *(uint2*)dst = make_uint2(0x3F803F80u, 0x3F803F80u);
    }

    // Q B-fragments: wave w owns strips (w*32 .. w*32+31), 2 strips of 16
    bf16x8 qf[2][2];
    #pragma unroll
    for (int s = 0; s < 2; ++s) {
        const u16* qp = Qb + (size_t)(q0 + w * 32 + s * 16 + ln) * HD + quad * 8;
        union { int4 i; bf16x8 b; } c0, c1;
        c0.i = *(const int4*)(qp);
        c1.i = *(const int4*)(qp + 32);
        qf[s][0] = c0.b; qf[s][1] = c1.b;
    }

    __syncthreads();   // ones rows visible; nothing critical in flight yet

    // prologue: stage tiles 0,1; bits for tile 0 issued AFTER the stages
    astage512(Kb, Vb, Ks0, Vs0, 0,  tid);
    astage512(Kb, Vb, Ks1, Vs1, 64, tid);
    size_t bb0 = ((size_t)b * SEQ + q0 + w * 32 + ln) * 16;
    size_t bb1 = bb0 + 256;
    unsigned long long bmn0 = bits[bb0];
    unsigned long long bmn1 = bits[bb1];

    floatx4 o[2][5] = {};   // [strip][dt], dt=4 is the l column

    for (int i = 0; i < 8; ++i) {
        // ---- tile 2i (buf0): queue [S(2i)2, b(2i)2, S(2i+1)2] -> drain S(2i)
        VMCNT4;
        BARX;
        {
            unsigned long long bc0 = bmn0, bc1 = bmn1;
            bmn0 = bits[bb0 + (2 * i + 1)];     // issued before stage(2i+2)
            bmn1 = bits[bb1 + (2 * i + 1)];
            attn_tile(Ks0, Vs0, Ps, qf, o, bc0, bc1, w, ln, quad);
        }
        BARX;                           // all waves done reading buf0
        if (i < 7) astage512(Kb, Vb, Ks0, Vs0, i * 128 + 128, tid);   // tile 2i+2
        // ---- tile 2i+1 (buf1)
        if (i < 7) { VMCNT4; } else { VMCNT0; }
        BARX;
        {
            unsigned long long bc0 = bmn0, bc1 = bmn1;
            if (i < 7) { bmn0 = bits[bb0 + (2 * i + 2)]; bmn1 = bits[bb1 + (2 * i + 2)]; }
            attn_tile(Ks1, Vs1, Ps, qf, o, bc0, bc1, w, ln, quad);
        }
        BARX;                           // all waves done reading buf1
        if (i < 7) astage512(Kb, Vb, Ks1, Vs1, i * 128 + 192, tid);   // tile 2i+3
    }

    #pragma unroll
    for (int s = 0; s < 2; ++s) {
        #pragma unroll
        for (int reg = 0; reg < 4; ++reg) {
            float l = __shfl(o[s][4][reg], lane & 48, 64);
            float inv = 1.0f / l;
            int m = q0 + w * 32 + s * 16 + quad * 4 + reg;
            #pragma unroll
            for (int dt = 0; dt < 4; ++dt)
                Aout[((size_t)b * SEQ + m) * EMB + h * HD + dt * 16 + ln] = f2b_rn(o[s][dt][reg] * inv);
        }
    }
}

// ---------------------------------------------------------------------------
// Kernel 3: output projection v2 — 64x256 tile (MxN), 256 blocks, 8 waves,
// depth-2 counted-vmcnt pipeline (verified round 5).  Unchanged.
// ---------------------------------------------------------------------------
#define OSTG_A(buf, kt) gload_lds16(Asrc + (size_t)(kt) * 64 + soff, (buf) + ldst)
#define OSTG_B(buf, c, kt) gload_lds16(Bsrc + (size_t)(c) * 65536 + (size_t)(kt) * 64 + soff, (buf) + (c) * 4096 + ldst)

__device__ __forceinline__ void op_tile(const u16* As, const u16* Bs,
                                        floatx4 (&acc)[4][2], int w, int ln, int quad)
{
    #pragma unroll
    for (int kk = 0; kk < 2; ++kk) {
        bf16x8 av[4], bv2[2];
        #pragma unroll
        for (int mf = 0; mf < 4; ++mf)
            av[mf] = ldsfrag(As, mf * 16 + ln, kk * 32 + quad * 8);
        #pragma unroll
        for (int nc = 0; nc < 2; ++nc)
            bv2[nc] = ldsfrag(Bs, w * 32 + nc * 16 + ln, kk * 32 + quad * 8);
        __builtin_amdgcn_s_setprio(1);
        #pragma unroll
        for (int mf = 0; mf < 4; ++mf)
            #pragma unroll
            for (int nc = 0; nc < 2; ++nc)
                acc[mf][nc] = __builtin_amdgcn_mfma_f32_16x16x32_bf16(av[mf], bv2[nc], acc[mf][nc], 0, 0, 0);
        __builtin_amdgcn_s_setprio(0);
    }
}

__global__ __launch_bounds__(512, 2) void out_proj(
    const u16* __restrict__ A,    // bf16 [4096][1024]
    const u16* __restrict__ Wo,   // bf16 [1024][1024] (n,k)
    const float* __restrict__ bo,
    float* __restrict__ Out)
{
    __shared__ u16 L[40960];                  // 80 KiB
    u16* A0s = L;
    u16* A1s = L + 4096;
    u16* B0s = L + 8192;
    u16* B1s = L + 24576;

    int gid = blockIdx.x;
    int xcd = gid & 7;                        // 0..7
    int j   = gid >> 3;                       // 0..31
    int m0 = (xcd * 8 + (j & 7)) * 64;        // m-tile 0..63
    int n0 = (j >> 3) * 256;                  // n-tile 0..3

    int tid = threadIdx.x;
    int w = tid >> 6, lane = tid & 63, quad = lane >> 4, ln = lane & 15;

    const u16* Asrc = A  + (size_t)m0 * EMB;
    const u16* Bsrc = Wo + (size_t)n0 * EMB;
    int sr = tid >> 3;
    int sc = ((tid & 7) ^ (sr & 7)) * 8;
    size_t soff = (size_t)sr * EMB + sc;
    int ldst = w * 512;

    // prologue: tiles 0 (buf0) and 1 (buf1), 5 chunks each
    OSTG_A(A0s, 0); OSTG_B(B0s, 0, 0); OSTG_B(B0s, 1, 0); OSTG_B(B0s, 2, 0); OSTG_B(B0s, 3, 0);
    OSTG_A(A1s, 1); OSTG_B(B1s, 0, 1); OSTG_B(B1s, 1, 1); OSTG_B(B1s, 2, 1); OSTG_B(B1s, 3, 1);

    floatx4 acc[4][2] = {};

    for (int i = 0; i < 8; ++i) {
        VMCNT5;                         // tile 2i landed (tile 2i+1's 5 in flight)
        BARX;
        op_tile(A0s, B0s, acc, w, ln, quad);
        BARX;                           // all waves done reading buf0
        if (i < 7) {
            int kt = 2 * i + 2;
            OSTG_A(A0s, kt); OSTG_B(B0s, 0, kt); OSTG_B(B0s, 1, kt); OSTG_B(B0s, 2, kt); OSTG_B(B0s, 3, kt);
        }
        if (i < 7) { VMCNT5; } else { VMCNT0; }
        BARX;
        op_tile(A1s, B1s, acc, w, ln, quad);
        BARX;                           // all waves done reading buf1
        if (i < 7) {
            int kt = 2 * i + 3;
            OSTG_A(A1s, kt); OSTG_B(B1s, 0, kt); OSTG_B(B1s, 1, kt); OSTG_B(B1s, 2, kt); OSTG_B(B1s, 3, kt);
        }
    }

    #pragma unroll
    for (int nc = 0; nc < 2; ++nc) {
        int n = n0 + w * 32 + nc * 16 + ln;
        float bb = bo[n];
        #pragma unroll
        for (int mf = 0; mf < 4; ++mf) {
            #pragma unroll
            for (int reg = 0; reg < 4; ++reg) {
                int m = m0 + mf * 16 + quad * 4 + reg;
                Out[(size_t)m * EMB + n] = acc[mf][nc][reg] + bb;
            }
        }
    }
}

// ---------------------------------------------------------------------------
extern "C" void kernel_launch(void* const* d_in, const int* in_sizes, int n_in,
                              void* d_out, int out_size, void* d_ws, size_t ws_size,
                              hipStream_t stream) {
    const float* x  = (const float*)d_in[0];
    const int*   mk = (const int*)d_in[1];
    const float* Wq = (const float*)d_in[2];
    const float* bq = (const float*)d_in[3];
    const float* Wk = (const float*)d_in[4];
    const float* bk = (const float*)d_in[5];
    const float* Wv = (const float*)d_in[6];
    const float* bv = (const float*)d_in[7];
    const float* Wo = (const float*)d_in[8];
    const float* bo = (const float*)d_in[9];
    float* out = (float*)d_out;

    const size_t MB = 1u << 20;
    char* ws = (char*)d_ws;
    u16* xb  = (u16*)ws;                                   // [ 0, 8M)
    u16* Wt  = (u16*)(ws + 8 * MB);                        // [ 8,14M)
    u16* Wob = (u16*)(ws + 14 * MB);                       // [14,16M)
    unsigned long long* bits = (unsigned long long*)(ws + 16 * MB); // [16,16.5M)
    u16* Qw  = (u16*)(ws + 16 * MB + 512 * 1024);          // [16.5,24.5M)
    u16* Kw  = (u16*)(ws + 24 * MB + 512 * 1024);          // [24.5,32.5M)
    u16* Vtw = (u16*)(ws + 32 * MB + 512 * 1024);          // [32.5,40.5M)
    u16* Ao  = xb;                                         // reuse: xb dead after qkv

    prep<<<5376, 256, 0, stream>>>(x, Wq, Wk, Wv, mk, xb, Wt, bits);
    qkv_gemm<<<256, 512, 0, stream>>>(xb, Wt, bq, bk, bv, Qw, Kw, Vtw);
    attn<<<512, 512, 0, stream>>>(Qw, Kw, Vtw, bits, Wo, Wob, Ao);
    out_proj<<<256, 512, 0, stream>>>(Ao, Wob, bo, out);
}